// Round 7
// baseline (175.232 us; speedup 1.0000x reference)
//
#include <hip/hip_runtime.h>
#include <hip/hip_bf16.h>

typedef unsigned short u16;
typedef unsigned int u32;
typedef __bf16 bf16x8 __attribute__((ext_vector_type(8)));
typedef float f32x4 __attribute__((ext_vector_type(4)));
typedef unsigned int u32x4 __attribute__((ext_vector_type(4)));
typedef unsigned int u32x2 __attribute__((ext_vector_type(2)));

#define NN 512
#define LL 40
#define DD 128
#define OO 256
#define KK 9
#define MHCL 34
#define TT 32
#define OC 32      // o-chunk per block
#define PSTR 136   // pept LDS row stride (u16)
#define MSTR 72    // mhcT LDS row stride (u16)
#define KSTR 136   // kern LDS row stride (u16)
#define LPAD 64    // padded l-dim for MFMA K
#define WPADL 64   // padded l-dim in preconverted W
#define KBUF (OC * KSTR)   // 4352 u16 per kern buffer

__device__ __forceinline__ u16 f2bf(float x) {
    unsigned int u = __builtin_bit_cast(unsigned int, x);
    u = (u + 0x7FFFu + ((u >> 16) & 1u)) >> 16;
    return (u16)u;
}
__device__ __forceinline__ u32 pk2(float a, float b) {
    __hip_bfloat162 h = __float22bfloat162_rn(make_float2(a, b)); // x = low half
    u32 r;
    __builtin_memcpy(&r, &h, 4);
    return r;
}
__device__ __forceinline__ bf16x8 lds_read8(const u16* p) {
    u32x4 r;
    __builtin_memcpy(&r, __builtin_assume_aligned(p, 16), 16);
    return __builtin_bit_cast(bf16x8, r);
}
__device__ __forceinline__ f32x4 mfma16(bf16x8 a, bf16x8 b, f32x4 c) {
    return __builtin_amdgcn_mfma_f32_16x16x32_bf16(a, b, c, 0, 0, 0);
}

// prologue: W fp32 [O][K][34] -> bf16 zero-padded [O][K][64] in ws
__global__ void w_convert(const float* __restrict__ wgt, u32* __restrict__ wp) {
    int i = blockIdx.x * 256 + threadIdx.x;        // 36864 u32 outputs
    if (i >= OO * KK * (WPADL / 2)) return;
    int o = i / (KK * (WPADL / 2));
    int r = i - o * (KK * (WPADL / 2));
    int k = r >> 5;
    int lp = (r & 31) << 1;
    const float* src = wgt + ((size_t)o * KK + k) * MHCL;
    float a = (lp     < MHCL) ? src[lp]     : 0.f;
    float b = (lp + 1 < MHCL) ? src[lp + 1] : 0.f;
    wp[i] = pk2(a, b);
}

template<bool PRE>
__global__ __launch_bounds__(256, 4)
void iconv_kernel(const float* __restrict__ pept,
                  const float* __restrict__ mhc,
                  const float* __restrict__ wgt,
                  const u16* __restrict__ wp,
                  const float* __restrict__ bias,
                  float* __restrict__ out)
{
    // LDS: 18432 + 10880 = 29312 B -> 4+ blocks/CU (launch_bounds 4)
    __shared__ __align__(16) u16 s_uni[DD * MSTR];   // mhcT[128][72] -> kern dbuf[2][32][136] -> red f32[4][32][33]
    __shared__ __align__(16) u16 s_pept[LL * PSTR];

    const int tid  = threadIdx.x;
    const int wave = tid >> 6;
    const int lane = tid & 63;
    const int quad = lane >> 4;
    const int l16  = lane & 15;

    const int n      = blockIdx.x >> 3;
    const int o_base = (blockIdx.x & 7) * OC;

    // ---- stage 0: staging, fp32 -> bf16 ----
    {
        const float* pg = pept + (size_t)n * LL * DD;
        #pragma unroll 1
        for (int i = tid; i < (LL * DD) / 4; i += 256) {
            int row = i >> 5, c4 = (i & 31) << 2;
            f32x4 v;
            __builtin_memcpy(&v, __builtin_assume_aligned(pg + row * DD + c4, 16), 16);
            u32x2 h = { pk2(v[0], v[1]), pk2(v[2], v[3]) };
            __builtin_memcpy(__builtin_assume_aligned(&s_pept[row * PSTR + c4], 8), &h, 8);
        }
        const float* mg = mhc + (size_t)n * MHCL * DD;
        #pragma unroll 1
        for (int i = tid; i < MHCL * DD; i += 256) {       // transpose-scatter
            int l = i >> 7, d = i & 127;
            s_uni[d * MSTR + l] = f2bf(mg[i]);
        }
        #pragma unroll 1
        for (int i = tid; i < DD * (LPAD - MHCL); i += 256) { // zero-pad l in [34,64)
            int d = i / 30, l = MHCL + (i - d * 30);
            s_uni[d * MSTR + l] = 0;
        }
    }
    __syncthreads();

    // ---- k-invariant mhc A-fragments into registers: wave owns d in [wave*32, wave*32+32) ----
    bf16x8 aF[2][2];   // [nt-local][ki]; A[m=d][kdim=l]
    #pragma unroll
    for (int ntl = 0; ntl < 2; ++ntl) {
        const int d = (wave * 2 + ntl) * 16 + l16;
        aF[ntl][0] = lds_read8(&s_uni[d * MSTR + quad * 8]);
        aF[ntl][1] = lds_read8(&s_uni[d * MSTR + 32 + quad * 8]);
    }
    __syncthreads();   // mhcT region dead -> kern double buffer

    u16* const kb0 = s_uni;
    u16* const kb1 = s_uni + KBUF;

    auto loadW = [&](int k, bf16x8 wF[2][2]) {
        if (PRE) {
            #pragma unroll
            for (int mt = 0; mt < 2; ++mt) {
                const u16* wr = wp + ((size_t)(o_base + mt * 16 + l16) * KK + k) * WPADL;
                u32x4 r0, r1;
                __builtin_memcpy(&r0, __builtin_assume_aligned(wr + quad * 8, 16), 16);
                __builtin_memcpy(&r1, __builtin_assume_aligned(wr + 32 + quad * 8, 16), 16);
                wF[mt][0] = __builtin_bit_cast(bf16x8, r0);
                wF[mt][1] = __builtin_bit_cast(bf16x8, r1);
            }
        } else {
            #pragma unroll
            for (int mt = 0; mt < 2; ++mt) {
                const float* wrow = wgt + ((size_t)(o_base + mt * 16 + l16) * KK + k) * MHCL;
                float w8[8];
                __builtin_memcpy(w8, __builtin_assume_aligned(wrow + quad * 8, 8), 32);
                u16 h0[8];
                #pragma unroll
                for (int j = 0; j < 8; ++j) h0[j] = f2bf(w8[j]);
                __builtin_memcpy(&wF[mt][0], h0, 16);
                u16 h1[8] = {0,0,0,0,0,0,0,0};
                if (quad == 0) { h1[0] = f2bf(wrow[32]); h1[1] = f2bf(wrow[33]); }
                __builtin_memcpy(&wF[mt][1], h1, 16);
            }
        }
    };

    // stage1: this wave computes kern rows d in its slice for all o' (2 nt tiles, 8 MFMA, 4 b64 writes)
    auto stage1 = [&](const bf16x8 wF[2][2], u16* kbuf) {
        #pragma unroll
        for (int ntl = 0; ntl < 2; ++ntl) {
            const int nt = wave * 2 + ntl;
            f32x4 c0 = {0.f,0.f,0.f,0.f}, c1 = c0;
            #pragma unroll
            for (int ki = 0; ki < 2; ++ki) {
                c0 = mfma16(aF[ntl][ki], wF[0][ki], c0);   // C[d_local][o' 0..15]
                c1 = mfma16(aF[ntl][ki], wF[1][ki], c1);   // C[d_local][o' 16..31]
            }
            u32x2 p0 = { pk2(fmaxf(c0[0], 0.f), fmaxf(c0[1], 0.f)),
                         pk2(fmaxf(c0[2], 0.f), fmaxf(c0[3], 0.f)) };
            u32x2 p1 = { pk2(fmaxf(c1[0], 0.f), fmaxf(c1[1], 0.f)),
                         pk2(fmaxf(c1[2], 0.f), fmaxf(c1[3], 0.f)) };
            __builtin_memcpy(__builtin_assume_aligned(&kbuf[l16 * KSTR + nt * 16 + quad * 4], 8), &p0, 8);
            __builtin_memcpy(__builtin_assume_aligned(&kbuf[(16 + l16) * KSTR + nt * 16 + quad * 4], 8), &p1, 8);
        }
    };

    // acc_ij[r] = out[t = i*16 + quad*4 + r][o' = j*16 + l16], partial over d-chunk = wave
    f32x4 acc00 = {0.f,0.f,0.f,0.f}, acc01 = acc00, acc10 = acc00, acc11 = acc00;
    const int off = wave * 32 + quad * 8;   // this wave's d-chunk column offset

    {
        bf16x8 wF0[2][2];
        loadW(0, wF0);
        stage1(wF0, kb0);
    }
    __syncthreads();

    for (int k = 0; k < KK; ++k) {
        bf16x8 wFn[2][2];
        if (k < KK - 1) loadW(k + 1, wFn);           // issue global loads early
        u16* const kc = (k & 1) ? kb1 : kb0;
        // stage 2: A=pept (m=t), B=kern (n=o'), kdim = this wave's 32 d
        bf16x8 bk0 = lds_read8(&kc[l16 * KSTR + off]);
        bf16x8 bk1 = lds_read8(&kc[(16 + l16) * KSTR + off]);
        bf16x8 ap0 = lds_read8(&s_pept[(k + l16) * PSTR + off]);
        bf16x8 ap1 = lds_read8(&s_pept[(k + 16 + l16) * PSTR + off]);
        acc00 = mfma16(ap0, bk0, acc00);
        acc01 = mfma16(ap0, bk1, acc01);
        acc10 = mfma16(ap1, bk0, acc10);
        acc11 = mfma16(ap1, bk1, acc11);
        if (k < KK - 1) stage1(wFn, (k & 1) ? kb0 : kb1);
        __syncthreads();   // kern(k+1) ready; stage2(k) reads drained before overwrite at k+2
    }

    // ---- cross-wave (d-chunk) reduction: red = f32[4][t=32][o'=33] over s_uni ----
    float* red = (float*)s_uni;
    {
        float* rw = red + wave * (TT * 33);
        #pragma unroll
        for (int r = 0; r < 4; ++r) {
            rw[(quad * 4 + r) * 33 + l16]           = acc00[r];
            rw[(quad * 4 + r) * 33 + 16 + l16]      = acc01[r];
            rw[(16 + quad * 4 + r) * 33 + l16]      = acc10[r];
            rw[(16 + quad * 4 + r) * 33 + 16 + l16] = acc11[r];
        }
    }
    __syncthreads();

    {
        const int o  = tid >> 3;        // 0..31
        const int t0 = (tid & 7) * 4;   // 0,4,...,28
        const float bv = bias[o_base + o];
        f32x4 res;
        #pragma unroll
        for (int j = 0; j < 4; ++j) {
            int idx = (t0 + j) * 33 + o;
            res[j] = red[idx] + red[TT * 33 + idx] + red[2 * TT * 33 + idx]
                   + red[3 * TT * 33 + idx] + bv;
        }
        float* op = out + ((size_t)n * OO + o_base + o) * TT + t0;
        __builtin_memcpy(__builtin_assume_aligned(op, 16), &res, 16);
    }
}

extern "C" void kernel_launch(void* const* d_in, const int* in_sizes, int n_in,
                              void* d_out, int out_size, void* d_ws, size_t ws_size,
                              hipStream_t stream) {
    const float* pept = (const float*)d_in[0];
    const float* mhc  = (const float*)d_in[1];
    const float* wgt  = (const float*)d_in[2];
    const float* bias = (const float*)d_in[3];
    float* out = (float*)d_out;
    dim3 grid(NN * (OO / OC));   // 4096 blocks: (n, o-chunk)
    dim3 block(256);             // 4 waves

    const size_t w_bytes = (size_t)OO * KK * WPADL * sizeof(u16); // 294,912
    if (ws_size >= w_bytes) {
        w_convert<<<dim3((OO * KK * (WPADL / 2) + 255) / 256), block, 0, stream>>>(wgt, (u32*)d_ws);
        iconv_kernel<true><<<grid, block, 0, stream>>>(pept, mhc, wgt, (const u16*)d_ws, bias, out);
    } else {
        iconv_kernel<false><<<grid, block, 0, stream>>>(pept, mhc, wgt, nullptr, bias, out);
    }
}

// Round 8
// 154.474 us; speedup vs baseline: 1.1344x; 1.1344x over previous
//
#include <hip/hip_runtime.h>
#include <hip/hip_bf16.h>

typedef unsigned short u16;
typedef unsigned int u32;
typedef __bf16 bf16x8 __attribute__((ext_vector_type(8)));
typedef float f32x4 __attribute__((ext_vector_type(4)));
typedef unsigned int u32x4 __attribute__((ext_vector_type(4)));
typedef unsigned int u32x2 __attribute__((ext_vector_type(2)));

#define NN 512
#define LL 40
#define DD 128
#define OO 256
#define KK 9
#define MHCL 34
#define TT 32
#define OC 32      // o-chunk per oc-iteration
#define PSTR 136   // pept LDS row stride (u16)
#define MSTR 72    // mhcT LDS row stride (u16)
#define KSTR 136   // kern LDS row stride (u16)
#define LPAD 64    // padded l-dim for MFMA K
#define WPADL 64   // padded l-dim in preconverted W
#define KBUF (OC * KSTR)   // 4352 u16 per kern buffer

__device__ __forceinline__ u16 f2bf(float x) {
    unsigned int u = __builtin_bit_cast(unsigned int, x);
    u = (u + 0x7FFFu + ((u >> 16) & 1u)) >> 16;
    return (u16)u;
}
__device__ __forceinline__ u32 pk2(float a, float b) {
    __hip_bfloat162 h = __float22bfloat162_rn(make_float2(a, b)); // x = low half
    u32 r;
    __builtin_memcpy(&r, &h, 4);
    return r;
}
__device__ __forceinline__ bf16x8 lds_read8(const u16* p) {
    u32x4 r;
    __builtin_memcpy(&r, __builtin_assume_aligned(p, 16), 16);
    return __builtin_bit_cast(bf16x8, r);
}
__device__ __forceinline__ f32x4 mfma16(bf16x8 a, bf16x8 b, f32x4 c) {
    return __builtin_amdgcn_mfma_f32_16x16x32_bf16(a, b, c, 0, 0, 0);
}

// prologue: W fp32 [O][K][34] -> bf16 zero-padded [O][K][64] in ws
__global__ void w_convert(const float* __restrict__ wgt, u32* __restrict__ wp) {
    int i = blockIdx.x * 256 + threadIdx.x;        // 36864 u32 outputs
    if (i >= OO * KK * (WPADL / 2)) return;
    int o = i / (KK * (WPADL / 2));
    int r = i - o * (KK * (WPADL / 2));
    int k = r >> 5;
    int lp = (r & 31) << 1;
    const float* src = wgt + ((size_t)o * KK + k) * MHCL;
    float a = (lp     < MHCL) ? src[lp]     : 0.f;
    float b = (lp + 1 < MHCL) ? src[lp + 1] : 0.f;
    wp[i] = pk2(a, b);
}

template<bool PRE>
__global__ __launch_bounds__(256, 4)
void iconv_kernel(const float* __restrict__ pept,
                  const float* __restrict__ mhc,
                  const float* __restrict__ wgt,
                  const u16* __restrict__ wp,
                  const float* __restrict__ bias,
                  float* __restrict__ out)
{
    // LDS: 18432 + 10880 = 29312 B
    __shared__ __align__(16) u16 s_uni[DD * MSTR];   // mhcT[128][72] -> kern dbuf[2][32][136] -> red f32[4][32][33]
    __shared__ __align__(16) u16 s_pept[LL * PSTR];

    const int tid  = threadIdx.x;
    const int wave = tid >> 6;
    const int lane = tid & 63;
    const int quad = lane >> 4;
    const int l16  = lane & 15;

    const int n = blockIdx.x;          // ONE block per sample: inputs fetched once globally

    // ---- stage 0: staging, fp32 -> bf16 ----
    {
        const float* pg = pept + (size_t)n * LL * DD;
        #pragma unroll 1
        for (int i = tid; i < (LL * DD) / 4; i += 256) {
            int row = i >> 5, c4 = (i & 31) << 2;
            f32x4 v;
            __builtin_memcpy(&v, __builtin_assume_aligned(pg + row * DD + c4, 16), 16);
            u32x2 h = { pk2(v[0], v[1]), pk2(v[2], v[3]) };
            __builtin_memcpy(__builtin_assume_aligned(&s_pept[row * PSTR + c4], 8), &h, 8);
        }
        const float* mg = mhc + (size_t)n * MHCL * DD;
        #pragma unroll 1
        for (int i = tid; i < MHCL * DD; i += 256) {       // transpose-scatter
            int l = i >> 7, d = i & 127;
            s_uni[d * MSTR + l] = f2bf(mg[i]);
        }
        #pragma unroll 1
        for (int i = tid; i < DD * (LPAD - MHCL); i += 256) { // zero-pad l in [34,64)
            int d = i / 30, l = MHCL + (i - d * 30);
            s_uni[d * MSTR + l] = 0;
        }
    }
    __syncthreads();

    // ---- k-invariant mhc A-fragments into registers: wave owns d in [wave*32, wave*32+32) ----
    bf16x8 aF[2][2];   // [nt-local][ki]; A[m=d][kdim=l]
    #pragma unroll
    for (int ntl = 0; ntl < 2; ++ntl) {
        const int d = (wave * 2 + ntl) * 16 + l16;
        aF[ntl][0] = lds_read8(&s_uni[d * MSTR + quad * 8]);
        aF[ntl][1] = lds_read8(&s_uni[d * MSTR + 32 + quad * 8]);
    }
    __syncthreads();   // mhcT region dead -> kern double buffer

    u16* const kb0 = s_uni;
    u16* const kb1 = s_uni + KBUF;

    auto loadW = [&](int o_base, int k, bf16x8 wF[2][2]) {
        if (PRE) {
            #pragma unroll
            for (int mt = 0; mt < 2; ++mt) {
                const u16* wr = wp + ((size_t)(o_base + mt * 16 + l16) * KK + k) * WPADL;
                u32x4 r0, r1;
                __builtin_memcpy(&r0, __builtin_assume_aligned(wr + quad * 8, 16), 16);
                __builtin_memcpy(&r1, __builtin_assume_aligned(wr + 32 + quad * 8, 16), 16);
                wF[mt][0] = __builtin_bit_cast(bf16x8, r0);
                wF[mt][1] = __builtin_bit_cast(bf16x8, r1);
            }
        } else {
            #pragma unroll
            for (int mt = 0; mt < 2; ++mt) {
                const float* wrow = wgt + ((size_t)(o_base + mt * 16 + l16) * KK + k) * MHCL;
                float w8[8];
                __builtin_memcpy(w8, __builtin_assume_aligned(wrow + quad * 8, 8), 32);
                u16 h0[8];
                #pragma unroll
                for (int j = 0; j < 8; ++j) h0[j] = f2bf(w8[j]);
                __builtin_memcpy(&wF[mt][0], h0, 16);
                u16 h1[8] = {0,0,0,0,0,0,0,0};
                if (quad == 0) { h1[0] = f2bf(wrow[32]); h1[1] = f2bf(wrow[33]); }
                __builtin_memcpy(&wF[mt][1], h1, 16);
            }
        }
    };

    // stage1: this wave computes kern rows d in its slice for all o' (2 nt tiles, 8 MFMA, 4 b64 writes)
    auto stage1 = [&](const bf16x8 wF[2][2], u16* kbuf) {
        #pragma unroll
        for (int ntl = 0; ntl < 2; ++ntl) {
            const int nt = wave * 2 + ntl;
            f32x4 c0 = {0.f,0.f,0.f,0.f}, c1 = c0;
            #pragma unroll
            for (int ki = 0; ki < 2; ++ki) {
                c0 = mfma16(aF[ntl][ki], wF[0][ki], c0);   // C[d_local][o' 0..15]
                c1 = mfma16(aF[ntl][ki], wF[1][ki], c1);   // C[d_local][o' 16..31]
            }
            u32x2 p0 = { pk2(fmaxf(c0[0], 0.f), fmaxf(c0[1], 0.f)),
                         pk2(fmaxf(c0[2], 0.f), fmaxf(c0[3], 0.f)) };
            u32x2 p1 = { pk2(fmaxf(c1[0], 0.f), fmaxf(c1[1], 0.f)),
                         pk2(fmaxf(c1[2], 0.f), fmaxf(c1[3], 0.f)) };
            __builtin_memcpy(__builtin_assume_aligned(&kbuf[l16 * KSTR + nt * 16 + quad * 4], 8), &p0, 8);
            __builtin_memcpy(__builtin_assume_aligned(&kbuf[(16 + l16) * KSTR + nt * 16 + quad * 4], 8), &p1, 8);
        }
    };

    const int off = wave * 32 + quad * 8;   // this wave's d-chunk column offset

    #pragma unroll 1
    for (int oc = 0; oc < OO / OC; ++oc) {
        const int o_base = oc * OC;
        // acc_ij[r] = out[t = i*16 + quad*4 + r][o' = j*16 + l16], partial over d-chunk = wave
        f32x4 acc00 = {0.f,0.f,0.f,0.f}, acc01 = acc00, acc10 = acc00, acc11 = acc00;

        {
            bf16x8 wF0[2][2];
            loadW(o_base, 0, wF0);
            stage1(wF0, kb0);
        }
        __syncthreads();

        for (int k = 0; k < KK; ++k) {
            bf16x8 wFn[2][2];
            if (k < KK - 1) loadW(o_base, k + 1, wFn);   // issue global loads early
            u16* const kc = (k & 1) ? kb1 : kb0;
            // stage 2: A=pept (m=t), B=kern (n=o'), kdim = this wave's 32 d
            bf16x8 bk0 = lds_read8(&kc[l16 * KSTR + off]);
            bf16x8 bk1 = lds_read8(&kc[(16 + l16) * KSTR + off]);
            bf16x8 ap0 = lds_read8(&s_pept[(k + l16) * PSTR + off]);
            bf16x8 ap1 = lds_read8(&s_pept[(k + 16 + l16) * PSTR + off]);
            acc00 = mfma16(ap0, bk0, acc00);
            acc01 = mfma16(ap0, bk1, acc01);
            acc10 = mfma16(ap1, bk0, acc10);
            acc11 = mfma16(ap1, bk1, acc11);
            if (k < KK - 1) stage1(wFn, (k & 1) ? kb0 : kb1);
            __syncthreads();   // kern(k+1) ready; stage2(k) reads drained before overwrite
        }

        // ---- cross-wave (d-chunk) reduction: red = f32[4][t=32][o'=33] over s_uni ----
        float* red = (float*)s_uni;
        {
            float* rw = red + wave * (TT * 33);
            #pragma unroll
            for (int r = 0; r < 4; ++r) {
                rw[(quad * 4 + r) * 33 + l16]           = acc00[r];
                rw[(quad * 4 + r) * 33 + 16 + l16]      = acc01[r];
                rw[(16 + quad * 4 + r) * 33 + l16]      = acc10[r];
                rw[(16 + quad * 4 + r) * 33 + 16 + l16] = acc11[r];
            }
        }
        __syncthreads();

        {
            const int o  = tid >> 3;        // 0..31
            const int t0 = (tid & 7) * 4;   // 0,4,...,28
            const float bv = bias[o_base + o];
            f32x4 res;
            #pragma unroll
            for (int j = 0; j < 4; ++j) {
                int idx = (t0 + j) * 33 + o;
                res[j] = red[idx] + red[TT * 33 + idx] + red[2 * TT * 33 + idx]
                       + red[3 * TT * 33 + idx] + bv;
            }
            float* op = out + ((size_t)n * OO + o_base + o) * TT + t0;
            __builtin_memcpy(__builtin_assume_aligned(op, 16), &res, 16);
        }
        __syncthreads();   // red reads drained before next oc's stage1 writes kb0
    }
}

extern "C" void kernel_launch(void* const* d_in, const int* in_sizes, int n_in,
                              void* d_out, int out_size, void* d_ws, size_t ws_size,
                              hipStream_t stream) {
    const float* pept = (const float*)d_in[0];
    const float* mhc  = (const float*)d_in[1];
    const float* wgt  = (const float*)d_in[2];
    const float* bias = (const float*)d_in[3];
    float* out = (float*)d_out;
    dim3 block(256);             // 4 waves

    const size_t w_bytes = (size_t)OO * KK * WPADL * sizeof(u16); // 294,912
    if (ws_size >= w_bytes) {
        w_convert<<<dim3((OO * KK * (WPADL / 2) + 255) / 256), block, 0, stream>>>(wgt, (u32*)d_ws);
        iconv_kernel<true><<<dim3(NN), block, 0, stream>>>(pept, mhc, wgt, (const u16*)d_ws, bias, out);
    } else {
        iconv_kernel<false><<<dim3(NN), block, 0, stream>>>(pept, mhc, wgt, nullptr, bias, out);
    }
}

// Round 9
// 147.766 us; speedup vs baseline: 1.1859x; 1.0454x over previous
//
#include <hip/hip_runtime.h>
#include <hip/hip_bf16.h>

typedef unsigned short u16;
typedef unsigned int u32;
typedef __bf16 bf16x8 __attribute__((ext_vector_type(8)));
typedef float f32x4 __attribute__((ext_vector_type(4)));
typedef unsigned int u32x4 __attribute__((ext_vector_type(4)));
typedef unsigned int u32x2 __attribute__((ext_vector_type(2)));

#define NN 512
#define LL 40
#define DD 128
#define OO 256
#define KK 9
#define MHCL 34
#define TT 32
#define OC 32      // o-chunk per oc-iteration
#define OCPB 4     // oc iterations per block (oc-half)
#define PSTR 136   // pept LDS row stride (u16)
#define MSTR 72    // mhcT LDS row stride (u16)
#define KSTR 136   // kern LDS row stride (u16)
#define LPAD 64    // padded l-dim for MFMA K
#define WPADL 64   // padded l-dim in preconverted W

__device__ __forceinline__ u16 f2bf(float x) {
    unsigned int u = __builtin_bit_cast(unsigned int, x);
    u = (u + 0x7FFFu + ((u >> 16) & 1u)) >> 16;
    return (u16)u;
}
__device__ __forceinline__ u32 pk2(float a, float b) {
    __hip_bfloat162 h = __float22bfloat162_rn(make_float2(a, b)); // x = low half
    u32 r;
    __builtin_memcpy(&r, &h, 4);
    return r;
}
__device__ __forceinline__ bf16x8 lds_read8(const u16* p) {
    u32x4 r;
    __builtin_memcpy(&r, __builtin_assume_aligned(p, 16), 16);
    return __builtin_bit_cast(bf16x8, r);
}
__device__ __forceinline__ f32x4 mfma16(bf16x8 a, bf16x8 b, f32x4 c) {
    return __builtin_amdgcn_mfma_f32_16x16x32_bf16(a, b, c, 0, 0, 0);
}

// prologue: W fp32 [O][K][34] -> bf16 zero-padded [O][K][64] in ws
__global__ void w_convert(const float* __restrict__ wgt, u32* __restrict__ wp) {
    int i = blockIdx.x * 256 + threadIdx.x;        // 36864 u32 outputs
    if (i >= OO * KK * (WPADL / 2)) return;
    int o = i / (KK * (WPADL / 2));
    int r = i - o * (KK * (WPADL / 2));
    int k = r >> 5;
    int lp = (r & 31) << 1;
    const float* src = wgt + ((size_t)o * KK + k) * MHCL;
    float a = (lp     < MHCL) ? src[lp]     : 0.f;
    float b = (lp + 1 < MHCL) ? src[lp + 1] : 0.f;
    wp[i] = pk2(a, b);
}

template<bool PRE>
__global__ __launch_bounds__(256, 4)
void iconv_kernel(const float* __restrict__ pept,
                  const float* __restrict__ mhc,
                  const float* __restrict__ wgt,
                  const u16* __restrict__ wp,
                  const float* __restrict__ bias,
                  float* __restrict__ out)
{
    // LDS: 18432 + 10880 = 29312 B -> 4 blocks/CU with launch_bounds(256,4)
    __shared__ __align__(16) u16 s_uni[DD * MSTR];   // mhcT[128][72] -> kern[32][136] -> red f32[4][32][33]
    __shared__ __align__(16) u16 s_pept[LL * PSTR];

    const int tid  = threadIdx.x;
    const int wave = tid >> 6;
    const int lane = tid & 63;
    const int quad = lane >> 4;
    const int l16  = lane & 15;

    const int n       = blockIdx.x >> 1;          // 2 blocks per sample
    const int oc_half = blockIdx.x & 1;           // each does 4 of the 8 o-chunks

    // ---- stage 0: staging, fp32 -> bf16 ----
    {
        const float* pg = pept + (size_t)n * LL * DD;
        #pragma unroll 1
        for (int i = tid; i < (LL * DD) / 4; i += 256) {
            int row = i >> 5, c4 = (i & 31) << 2;
            f32x4 v;
            __builtin_memcpy(&v, __builtin_assume_aligned(pg + row * DD + c4, 16), 16);
            u32x2 h = { pk2(v[0], v[1]), pk2(v[2], v[3]) };
            __builtin_memcpy(__builtin_assume_aligned(&s_pept[row * PSTR + c4], 8), &h, 8);
        }
        const float* mg = mhc + (size_t)n * MHCL * DD;
        #pragma unroll 1
        for (int i = tid; i < MHCL * DD; i += 256) {       // transpose-scatter
            int l = i >> 7, d = i & 127;
            s_uni[d * MSTR + l] = f2bf(mg[i]);
        }
        #pragma unroll 1
        for (int i = tid; i < DD * (LPAD - MHCL); i += 256) { // zero-pad l in [34,64)
            int d = i / 30, l = MHCL + (i - d * 30);
            s_uni[d * MSTR + l] = 0;
        }
    }
    __syncthreads();

    // ---- k-invariant mhc A-fragments into registers: wave owns d in [wave*32, wave*32+32) ----
    bf16x8 aF[2][2];   // [nt-local][ki]; A[m=d][kdim=l]
    #pragma unroll
    for (int ntl = 0; ntl < 2; ++ntl) {
        const int d = (wave * 2 + ntl) * 16 + l16;
        aF[ntl][0] = lds_read8(&s_uni[d * MSTR + quad * 8]);
        aF[ntl][1] = lds_read8(&s_uni[d * MSTR + 32 + quad * 8]);
    }
    __syncthreads();   // mhcT region dead -> kern buffer (wave-private columns, no dbuf needed)

    u16* const kb = s_uni;

    auto loadW = [&](int o_base, int k, bf16x8 wF[2][2]) {
        if (PRE) {
            #pragma unroll
            for (int mt = 0; mt < 2; ++mt) {
                const u16* wr = wp + ((size_t)(o_base + mt * 16 + l16) * KK + k) * WPADL;
                u32x4 r0, r1;
                __builtin_memcpy(&r0, __builtin_assume_aligned(wr + quad * 8, 16), 16);
                __builtin_memcpy(&r1, __builtin_assume_aligned(wr + 32 + quad * 8, 16), 16);
                wF[mt][0] = __builtin_bit_cast(bf16x8, r0);
                wF[mt][1] = __builtin_bit_cast(bf16x8, r1);
            }
        } else {
            #pragma unroll
            for (int mt = 0; mt < 2; ++mt) {
                const float* wrow = wgt + ((size_t)(o_base + mt * 16 + l16) * KK + k) * MHCL;
                float w8[8];
                __builtin_memcpy(w8, __builtin_assume_aligned(wrow + quad * 8, 8), 32);
                u16 h0[8];
                #pragma unroll
                for (int j = 0; j < 8; ++j) h0[j] = f2bf(w8[j]);
                __builtin_memcpy(&wF[mt][0], h0, 16);
                u16 h1[8] = {0,0,0,0,0,0,0,0};
                if (quad == 0) { h1[0] = f2bf(wrow[32]); h1[1] = f2bf(wrow[33]); }
                __builtin_memcpy(&wF[mt][1], h1, 16);
            }
        }
    };

    // stage1: wave computes kern rows (all o') for its d-columns [32*wave, 32*wave+32) — private region
    auto stage1 = [&](const bf16x8 wF[2][2]) {
        #pragma unroll
        for (int ntl = 0; ntl < 2; ++ntl) {
            const int nt = wave * 2 + ntl;
            f32x4 c0 = {0.f,0.f,0.f,0.f}, c1 = c0;
            #pragma unroll
            for (int ki = 0; ki < 2; ++ki) {
                c0 = mfma16(aF[ntl][ki], wF[0][ki], c0);   // C[d_local][o' 0..15]
                c1 = mfma16(aF[ntl][ki], wF[1][ki], c1);   // C[d_local][o' 16..31]
            }
            u32x2 p0 = { pk2(fmaxf(c0[0], 0.f), fmaxf(c0[1], 0.f)),
                         pk2(fmaxf(c0[2], 0.f), fmaxf(c0[3], 0.f)) };
            u32x2 p1 = { pk2(fmaxf(c1[0], 0.f), fmaxf(c1[1], 0.f)),
                         pk2(fmaxf(c1[2], 0.f), fmaxf(c1[3], 0.f)) };
            __builtin_memcpy(__builtin_assume_aligned(&kb[l16 * KSTR + nt * 16 + quad * 4], 8), &p0, 8);
            __builtin_memcpy(__builtin_assume_aligned(&kb[(16 + l16) * KSTR + nt * 16 + quad * 4], 8), &p1, 8);
        }
    };

    const int off = wave * 32 + quad * 8;   // this wave's d-chunk column offset

    #pragma unroll 1
    for (int oci = 0; oci < OCPB; ++oci) {
        const int o_base = (oc_half * OCPB + oci) * OC;
        // acc_ij[r] = out[t = i*16 + quad*4 + r][o' = j*16 + l16], partial over d-chunk = wave
        f32x4 acc00 = {0.f,0.f,0.f,0.f}, acc01 = acc00, acc10 = acc00, acc11 = acc00;

        {
            bf16x8 wF0[2][2];
            loadW(o_base, 0, wF0);
            stage1(wF0);
        }

        // NO barriers: wave reads exactly the kern columns it wrote; same-wave LDS deps
        // are ordered by lgkmcnt. Waves drift freely -> latency pipelining across k.
        for (int k = 0; k < KK; ++k) {
            bf16x8 wFn[2][2];
            if (k < KK - 1) loadW(o_base, k + 1, wFn);   // issue global loads early
            // stage 2: A=pept (m=t), B=kern (n=o'), kdim = this wave's 32 d
            bf16x8 bk0 = lds_read8(&kb[l16 * KSTR + off]);
            bf16x8 bk1 = lds_read8(&kb[(16 + l16) * KSTR + off]);
            bf16x8 ap0 = lds_read8(&s_pept[(k + l16) * PSTR + off]);
            bf16x8 ap1 = lds_read8(&s_pept[(k + 16 + l16) * PSTR + off]);
            acc00 = mfma16(ap0, bk0, acc00);
            acc01 = mfma16(ap0, bk1, acc01);
            acc10 = mfma16(ap1, bk0, acc10);
            acc11 = mfma16(ap1, bk1, acc11);
            if (k < KK - 1) stage1(wFn);                 // overwrite own columns for k+1
        }

        __syncthreads();   // all waves done with kern/stage2 before red tramples s_uni
        // ---- cross-wave (d-chunk) reduction: red = f32[4][t=32][o'=33] over s_uni ----
        float* red = (float*)s_uni;
        {
            float* rw = red + wave * (TT * 33);
            #pragma unroll
            for (int r = 0; r < 4; ++r) {
                rw[(quad * 4 + r) * 33 + l16]           = acc00[r];
                rw[(quad * 4 + r) * 33 + 16 + l16]      = acc01[r];
                rw[(16 + quad * 4 + r) * 33 + l16]      = acc10[r];
                rw[(16 + quad * 4 + r) * 33 + 16 + l16] = acc11[r];
            }
        }
        __syncthreads();

        {
            const int o  = tid >> 3;        // 0..31
            const int t0 = (tid & 7) * 4;   // 0,4,...,28
            const float bv = bias[o_base + o];
            f32x4 res;
            #pragma unroll
            for (int j = 0; j < 4; ++j) {
                int idx = (t0 + j) * 33 + o;
                res[j] = red[idx] + red[TT * 33 + idx] + red[2 * TT * 33 + idx]
                       + red[3 * TT * 33 + idx] + bv;
            }
            float* op = out + ((size_t)n * OO + o_base + o) * TT + t0;
            __builtin_memcpy(__builtin_assume_aligned(op, 16), &res, 16);
        }
        __syncthreads();   // red reads drained before next oc's stage1 writes kern region
    }
}

extern "C" void kernel_launch(void* const* d_in, const int* in_sizes, int n_in,
                              void* d_out, int out_size, void* d_ws, size_t ws_size,
                              hipStream_t stream) {
    const float* pept = (const float*)d_in[0];
    const float* mhc  = (const float*)d_in[1];
    const float* wgt  = (const float*)d_in[2];
    const float* bias = (const float*)d_in[3];
    float* out = (float*)d_out;
    dim3 block(256);             // 4 waves

    const size_t w_bytes = (size_t)OO * KK * WPADL * sizeof(u16); // 294,912
    if (ws_size >= w_bytes) {
        w_convert<<<dim3((OO * KK * (WPADL / 2) + 255) / 256), block, 0, stream>>>(wgt, (u32*)d_ws);
        iconv_kernel<true><<<dim3(NN * 2), block, 0, stream>>>(pept, mhc, wgt, (const u16*)d_ws, bias, out);
    } else {
        iconv_kernel<false><<<dim3(NN * 2), block, 0, stream>>>(pept, mhc, wgt, nullptr, bias, out);
    }
}